// Round 2
// baseline (507.785 us; speedup 1.0000x reference)
//
#include <hip/hip_runtime.h>

// x: [B=4, C=8, H=128, W=128] f32 -> out: [B, C, 210, H*W] f32
// Channels 0..44   : v[j]*v[k],        j<=k       (pairs2, i-major lex order)
// Channels 45..209 : v[i]*(v[j]*v[k]), i<=j<=k    (pairs3, i-major lex order)
//
// Structure (R2): ONE BLOCK PER (plane, channel); each block writes its 64 KB
// channel-plane contiguously, recomputing its 2-3 taps from the L2-resident
// input plane. Store stream is memset-shaped (fill kernel proves 6.2 TB/s on
// this buffer).
//
// R3 fix: R2 fully unrolled 16 iterations -> ~45 independent float4 loads
// hoisted by the scheduler -> VGPR liveness blowup against the 128-reg cap
// (spill/serialize; kernel ~221 us vs ~75 us floor). Now: peel the two edge
// iterations, run the middle 14 at unroll 2, precompute per-tap offsets once,
// keep ~4 live float4s. __launch_bounds__(256,8) caps at 64 VGPR -> 32
// waves/CU of TLP to hide L2 latency.

#define HH 128
#define WW 128
#define LL (HH * WW)
#define NCH 210

__device__ __forceinline__ int tri9(int m) { return m * (m + 1) / 2; }

__device__ __forceinline__ float4 ldu(const float* __restrict__ p) {
    return *reinterpret_cast<const float4*>(p);
}

__device__ __forceinline__ float4 mul4(float4 a, float4 b) {
    return make_float4(a.x * b.x, a.y * b.y, a.z * b.z, a.w * b.w);
}

// Lane-edge window fixups: the 16B load was shifted to stay inside the row;
// shift values into window position and zero the padded element.
// dw is block-uniform; lo/hi are per-lane (wq==0 / wq==31).
__device__ __forceinline__ float4 fixw(float4 v, int dw, bool lo, bool hi) {
    if (dw == 0) {
        if (lo) { v.w = v.z; v.z = v.y; v.y = v.x; v.x = 0.f; }
    }
    if (dw == 2) {
        if (hi) { v.x = v.y; v.y = v.z; v.z = v.w; v.w = 0.f; }
    }
    return v;
}

__global__ __launch_bounds__(256, 8) void hoi_kernel(const float* __restrict__ x,
                                                     float* __restrict__ out) {
    const int ch    = blockIdx.x;   // 0..209
    const int plane = blockIdx.y;   // 0..31

    // Decode channel -> tap indices (block-uniform scalar loops).
    int A = 0, Bt = 0, Ct = 0;
    bool o3;
    {
        int c = ch;
        if (c < 45) {
            o3 = false;
            int j = 0;
            while (c >= 9 - j) { c -= 9 - j; ++j; }
            Bt = j; Ct = j + c;                 // out = v[Bt] * v[Ct]
        } else {
            o3 = true;
            c -= 45;
            int i = 0;
            while (c >= tri9(9 - i)) { c -= tri9(9 - i); ++i; }
            int j = i;
            while (c >= 9 - j) { c -= 9 - j; ++j; }
            A = i; Bt = j; Ct = j + c;          // out = v[A] * (v[Bt] * v[Ct])
        }
    }
    const int dhA = A / 3,  dwA = A % 3;
    const int dhB = Bt / 3, dwB = Bt % 3;
    const int dhC = Ct / 3, dwC = Ct % 3;

    const int tid = threadIdx.x;
    const int wq  = tid & 31;        // column-quad index: 32 quads cover a row
    const int w0  = wq << 2;
    const int hs  = tid >> 5;        // 0..7 row sub-index

    const bool lo = (wq == 0);
    const bool hi = (wq == 31);

    const float* __restrict__ xp = x + (size_t)plane * LL;
    float* __restrict__ op = out + ((size_t)plane * NCH + ch) * LL + hs * WW + w0;

    // Per-tap flat offset at iteration 0 (output row = hs), with the lane-edge
    // address shift folded in so every load stays inside its input row.
    int oB, oC, oA = 0;
    {
        const int fB = (dwB == 0 && lo) ? 1 : ((dwB == 2 && hi) ? -1 : 0);
        const int fC = (dwC == 0 && lo) ? 1 : ((dwC == 2 && hi) ? -1 : 0);
        oB = (hs + dhB - 1) * WW + (w0 + dwB - 1 + fB);
        oC = (hs + dhC - 1) * WW + (w0 + dwC - 1 + fC);
        if (o3) {
            const int fA = (dwA == 0 && lo) ? 1 : ((dwA == 2 && hi) ? -1 : 0);
            oA = (hs + dhA - 1) * WW + (w0 + dwA - 1 + fA);
        }
    }

    // ---- it = 0: output rows 0..7. Tap row is -1 iff hs==0 && dh==0:
    // clamp the address down a row (stays in-plane) and zero the value.
    {
        const bool e  = (hs == 0);
        const bool zB = e && (dhB == 0);
        const bool zC = e && (dhC == 0);
        float4 vb = ldu(xp + oB + (zB ? WW : 0));
        float4 vc = ldu(xp + oC + (zC ? WW : 0));
        vb = fixw(vb, dwB, lo, hi);
        vc = fixw(vc, dwC, lo, hi);
        if (zB) vb = make_float4(0.f, 0.f, 0.f, 0.f);
        if (zC) vc = make_float4(0.f, 0.f, 0.f, 0.f);
        float4 t = mul4(vb, vc);
        if (o3) {
            const bool zA = e && (dhA == 0);
            float4 va = ldu(xp + oA + (zA ? WW : 0));
            va = fixw(va, dwA, lo, hi);
            if (zA) va = make_float4(0.f, 0.f, 0.f, 0.f);
            t = mul4(va, t);
        }
        *reinterpret_cast<float4*>(op) = t;
    }

    // ---- it = 1..14: all tap rows in-range. Keep liveness small.
#pragma unroll 2
    for (int it = 1; it < 15; ++it) {
        const int d = it * 8 * WW;
        float4 vb = fixw(ldu(xp + oB + d), dwB, lo, hi);
        float4 vc = fixw(ldu(xp + oC + d), dwC, lo, hi);
        float4 t  = mul4(vb, vc);
        if (o3) {
            float4 va = fixw(ldu(xp + oA + d), dwA, lo, hi);
            t = mul4(va, t);
        }
        *reinterpret_cast<float4*>(op + d) = t;
    }

    // ---- it = 15: output rows 120..127. Tap row is 128 iff hs==7 && dh==2:
    // clamp the address up a row and zero the value.
    {
        const int  d  = 15 * 8 * WW;
        const bool e  = (hs == 7);
        const bool zB = e && (dhB == 2);
        const bool zC = e && (dhC == 2);
        float4 vb = ldu(xp + oB + d - (zB ? WW : 0));
        float4 vc = ldu(xp + oC + d - (zC ? WW : 0));
        vb = fixw(vb, dwB, lo, hi);
        vc = fixw(vc, dwC, lo, hi);
        if (zB) vb = make_float4(0.f, 0.f, 0.f, 0.f);
        if (zC) vc = make_float4(0.f, 0.f, 0.f, 0.f);
        float4 t = mul4(vb, vc);
        if (o3) {
            const bool zA = e && (dhA == 2);
            float4 va = ldu(xp + oA + d - (zA ? WW : 0));
            va = fixw(va, dwA, lo, hi);
            if (zA) va = make_float4(0.f, 0.f, 0.f, 0.f);
            t = mul4(va, t);
        }
        *reinterpret_cast<float4*>(op + d) = t;
    }
}

extern "C" void kernel_launch(void* const* d_in, const int* in_sizes, int n_in,
                              void* d_out, int out_size, void* d_ws, size_t ws_size,
                              hipStream_t stream) {
    const float* x = (const float*)d_in[0];
    float* out = (float*)d_out;

    const int nplanes = in_sizes[0] / LL;   // B*C = 32
    hoi_kernel<<<dim3(NCH, nplanes), 256, 0, stream>>>(x, out);
}

// Round 6
// 433.800 us; speedup vs baseline: 1.1706x; 1.1706x over previous
//
#include <hip/hip_runtime.h>

// x: [B=4, C=8, H=128, W=128] f32 -> out: [B, C, 210, H*W] f32
// Channels 0..44   : v[j]*v[k],        j<=k       (pairs2, i-major lex order)
// Channels 45..209 : v[i]*(v[j]*v[k]), i<=j<=k    (pairs3, i-major lex order)
//
// R6: R0 structure (best measured: kernel ~150 us = graded 432.7 minus the
// ~283 us harness poison-fill) + NONTEMPORAL stores.
// R5 failed to compile: __builtin_nontemporal_store requires a clang
// ext_vector pointer, not HIP's float4 class. (This same error is what killed
// R3/R4 — reported as "container failed" — not infra.) Fixed via v4f typedef;
// identical 16-byte layout, same global_store_dwordx4 but with the nt bit.
//
// Theory: the harness fill proves the non-allocating store path hits 6.2 TB/s
// on this buffer (1.7 GB written, FETCH_SIZE 14.5 KB). Our kernel's ~150 us
// is 2x the ~75 us pure-write floor because the 2^16 B channel stride makes
// a wave's ~105 store bursts congruent mod 64 KB -> identical L2 index bits
// 7..15 -> set/channel funneling. nt stores bypass L2 allocation.

#define HH 128
#define WW 128
#define LL (HH * WW)
#define NCH 210

typedef float v4f __attribute__((ext_vector_type(4)));

__host__ __device__ constexpr int ch2_idx(int i, int j) {
    // pairs2 lex index, i <= j
    return i * 9 - (i * (i - 1)) / 2 + (j - i);
}
__host__ __device__ constexpr int tri(int m) { return m * (m + 1) / 2; }
__host__ __device__ constexpr int ch3_idx(int i, int j, int k) {
    // 45 + lex index of (i,j,k), i <= j <= k
    int s = 0;
    for (int a = 0; a < i; ++a) s += tri(9 - a);
    for (int b = i; b < j; ++b) s += (9 - b);
    return 45 + s + (k - j);
}

__device__ __forceinline__ void st_nt(float* __restrict__ p, float4 t) {
    v4f q;
    q.x = t.x; q.y = t.y; q.z = t.z; q.w = t.w;
    __builtin_nontemporal_store(q, reinterpret_cast<v4f*>(p));
}

template <int JLO, int JHI>
__device__ __forceinline__ void emit(const float4 (&v)[9], float* __restrict__ obase) {
#pragma unroll
    for (int j = JLO; j < JHI; ++j) {
#pragma unroll
        for (int k = j; k < 9; ++k) {
            float4 t;
            t.x = v[j].x * v[k].x;
            t.y = v[j].y * v[k].y;
            t.z = v[j].z * v[k].z;
            t.w = v[j].w * v[k].w;
            st_nt(obase + ch2_idx(j, k) * LL, t);
#pragma unroll
            for (int i = 0; i <= j; ++i) {
                float4 q;
                q.x = v[i].x * t.x;
                q.y = v[i].y * t.y;
                q.z = v[i].z * t.z;
                q.w = v[i].w * t.w;
                st_nt(obase + ch3_idx(i, j, k) * LL, q);
            }
        }
    }
}

__global__ __launch_bounds__(256, 4) void hoi_kernel(const float* __restrict__ x,
                                                     float* __restrict__ out) {
    const int tid   = blockIdx.x * 256 + threadIdx.x;
    const int wq    = tid & 31;          // group of 4 columns
    const int h     = (tid >> 5) & 127;  // row
    const int plane = tid >> 12;         // b*C + c  (0..31)
    const int w0    = wq << 2;

    const float* __restrict__ xp = x + (size_t)plane * LL;

    // 3 rows x 6 cols neighborhood, zero-padded.
    float r[3][6];
#pragma unroll
    for (int dh = 0; dh < 3; ++dh) {
        const int hh = h + dh - 1;
        const bool hv = (hh >= 0) & (hh < HH);
#pragma unroll
        for (int dw = 0; dw < 6; ++dw) {
            const int ww = w0 + dw - 1;
            const bool wv = (ww >= 0) & (ww < WW);
            r[dh][dw] = (hv & wv) ? xp[hh * WW + ww] : 0.0f;
        }
    }

    // 9 taps, each a float4 sliding window over this thread's 4 pixels.
    float4 v[9];
#pragma unroll
    for (int dh = 0; dh < 3; ++dh) {
#pragma unroll
        for (int dw = 0; dw < 3; ++dw) {
            v[dh * 3 + dw] = make_float4(r[dh][dw], r[dh][dw + 1],
                                         r[dh][dw + 2], r[dh][dw + 3]);
        }
    }

    float* __restrict__ obase = out + (size_t)plane * NCH * LL + h * WW + w0;

    // Channel split across gridDim.y: j<4 -> 100 stores, j>=4 -> 110 stores.
    if (blockIdx.y == 0) {
        emit<0, 4>(v, obase);
    } else {
        emit<4, 9>(v, obase);
    }
}

extern "C" void kernel_launch(void* const* d_in, const int* in_sizes, int n_in,
                              void* d_out, int out_size, void* d_ws, size_t ws_size,
                              hipStream_t stream) {
    const float* x = (const float*)d_in[0];
    float* out = (float*)d_out;

    const int nplanes = in_sizes[0] / LL;          // B*C = 32
    const int total   = nplanes * HH * (WW / 4);   // one thread per 4 pixels
    const int block   = 256;
    const int gx      = (total + block - 1) / block;

    hoi_kernel<<<dim3(gx, 2), block, 0, stream>>>(x, out);
}